// Round 4
// baseline (463.240 us; speedup 1.0000x reference)
//
#include <hip/hip_runtime.h>
#include <math.h>

// GraphLoss: W=128, L=2001 -> chain of 2000 log-semiring 128x128 matrix products
// + masked dot. out = gold + LSE_{i,k}( -w_start[i] + M_total[i][k] - w_end[k] ).
//
// Phase A (chunk): 256 blocks x ~8 layers, right-to-left fold M <- T_l (x) M via
//   split-bf16 MFMA (3 terms: Ah*Bh + Ah*Bl + Al*Bh), rep M[i][k]=s[i]+log P[i][k],
//   P in [0,1] rowmax-normalized each layer, stored transposed Pt[k][i] in LDS.
//   Output: coalesced fp32 copy-out of Pt (already in the tree's [k][i] layout).
// Phase B: 4-ary MFMA tree (identity-init, 4 folds/block): 256->64->16->4.
// Phase C: final block folds last 4 + LSE + gold.
// All renormalized writebacks clamp >=0 (split-bf16 lo terms can push ~0 values
// slightly negative; log(negative) would NaN, log(0)=-inf is benign in LSE).

#define MATN  16384
#define NEDGE 32768256l
#define EPAD  136        // u16 row stride (272B = 17*16B: 16B-aligned, 2-way-free banks)

#define OFF_AP 0ul
#define OFF_AS (OFF_AP + 256ul*MATN)
#define OFF_BP (OFF_AS + 256ul*128)
#define OFF_BS (OFF_BP + 64ul*MATN)
#define OFF_GP (OFF_BS + 64ul*128)
// total = 5,284,096 floats = 21.1 MB of d_ws

typedef __attribute__((ext_vector_type(8))) short short8;
typedef __attribute__((ext_vector_type(4))) float f32x4;
typedef __attribute__((ext_vector_type(4))) unsigned short u16x4;

__device__ __forceinline__ unsigned short f2bf(float x){
  unsigned int u = __float_as_uint(x);
  unsigned int r = (u + 0x7FFFu + ((u >> 16) & 1u)) >> 16;
  return (unsigned short)r;
}
__device__ __forceinline__ float bf2f(unsigned short h){
  return __uint_as_float(((unsigned int)h) << 16);
}

// raw barrier: lgkmcnt(0) only (LDS visibility); global prefetch stays in flight.
__device__ __forceinline__ void sbar(){
  asm volatile("s_waitcnt lgkmcnt(0)" ::: "memory");
  __builtin_amdgcn_sched_barrier(0);
  __builtin_amdgcn_s_barrier();
  __builtin_amdgcn_sched_barrier(0);
}

#define MFMA3(d, ah, al, bh, bl) \
  d = __builtin_amdgcn_mfma_f32_16x16x32_bf16(ah, bh, d, 0,0,0); \
  d = __builtin_amdgcn_mfma_f32_16x16x32_bf16(ah, bl, d, 0,0,0); \
  d = __builtin_amdgcn_mfma_f32_16x16x32_bf16(al, bh, d, 0,0,0);

// ============================ Phase A: chunks ============================
__global__ __launch_bounds__(512, 2) void chunk_kernel(const float* __restrict__ w,
                                                       const int* __restrict__ gmask,
                                                       float* __restrict__ ws)
{
  __shared__ __align__(16) unsigned short Eh[128*EPAD];   // fresh layer hi
  __shared__ __align__(16) unsigned short El_[128*EPAD];  // fresh layer lo
  __shared__ __align__(16) unsigned short Ph[128*EPAD];   // running Pt[k][i] hi
  __shared__ __align__(16) unsigned short Pl_[128*EPAD];  // running Pt lo
  __shared__ __align__(16) float sArr[128];
  __shared__ __align__(16) float rbuf[128*4];             // cross-wave rowmax
  __shared__ float red[8];

  const int t = threadIdx.x;
  const int c = blockIdx.x;
  const int lo = (c < 208) ? c*8 : 1664 + (c-208)*7;     // 208*8 + 48*7 = 2000
  const int nl = (c < 208) ? 8 : 7;

  const int wid = t >> 6, ln = t & 63;
  const int l15 = ln & 15, lhi = ln >> 4;
  const int wr  = wid >> 2;   // 0..1 : 64-row band (i)
  const int wc  = wid & 3;    // 0..3 : 32-col band (k)

  float gold = 0.f;

  // initial load: LAST layer of chunk (right-to-left build)
  float4 cw[8]; int4 cm[8];
  {
    const float* wp = w     + 128l + (long)(lo + nl - 1)*MATN;
    const int*   mp = gmask + 128l + (long)(lo + nl - 1)*MATN;
    #pragma unroll
    for (int f = 0; f < 8; f++){
      cw[f] = ((const float4*)wp)[t + 512*f];
      cm[f] = ((const int4*)mp)[t + 512*f];
    }
  }

  // P = I (split bf16), s = 0
  {
    unsigned int* z0 = (unsigned int*)Ph;
    unsigned int* z1 = (unsigned int*)Pl_;
    for (int q = t; q < 128*EPAD/2; q += 512){ z0[q] = 0u; z1[q] = 0u; }
    if (t < 128) sArr[t] = 0.f;
  }
  sbar();
  if (t < 128) Ph[t*EPAD + t] = 0x3F80;   // bf16 1.0
  sbar();

  for (int it = 0; it < nl; ++it){
    // ---- consume layer: gold + F[i][j] = s[j] - w[i][j]  (frees cw/cm)
    float F[8][4];
    float lmax = -INFINITY;
    #pragma unroll
    for (int f = 0; f < 8; f++){
      const int g = t + 512*f;
      const float4 wv = cw[f]; const int4 mv = cm[f];
      gold += (mv.x ? wv.x : 0.f) + (mv.y ? wv.y : 0.f)
            + (mv.z ? wv.z : 0.f) + (mv.w ? wv.w : 0.f);
      const float4 sv = *(const float4*)&sArr[(g & 31)*4];
      F[f][0] = sv.x - wv.x; F[f][1] = sv.y - wv.y;
      F[f][2] = sv.z - wv.z; F[f][3] = sv.w - wv.w;
      lmax = fmaxf(lmax, fmaxf(fmaxf(F[f][0],F[f][1]), fmaxf(F[f][2],F[f][3])));
    }
    // ---- prefetch next layer ASAP (stays in flight across raw barriers)
    if (it + 1 < nl){
      const float* wp = w     + 128l + (long)(lo + nl - 2 - it)*MATN;
      const int*   mp = gmask + 128l + (long)(lo + nl - 2 - it)*MATN;
      #pragma unroll
      for (int f = 0; f < 8; f++){
        cw[f] = ((const float4*)wp)[t + 512*f];
        cm[f] = ((const int4*)mp)[t + 512*f];
      }
    }
    // ---- block max of F
    #pragma unroll
    for (int m = 1; m <= 32; m <<= 1) lmax = fmaxf(lmax, __shfl_xor(lmax, m, 64));
    if (ln == 0) red[wid] = lmax;
    sbar();
    float mF = red[0];
    #pragma unroll
    for (int q = 1; q < 8; q++) mF = fmaxf(mF, red[q]);

    // ---- E = exp(F - mF), split hi/lo bf16 -> LDS
    #pragma unroll
    for (int f = 0; f < 8; f++){
      const int g = t + 512*f;
      const int row = g >> 5, c4 = g & 31;
      u16x4 hv, lv;
      #pragma unroll
      for (int e = 0; e < 4; e++){
        const float x = __expf(F[f][e] - mF);
        const unsigned short h = f2bf(x);
        hv[e] = h; lv[e] = f2bf(x - bf2f(h));
      }
      *(u16x4*)&Eh[row*EPAD + c4*4]  = hv;
      *(u16x4*)&El_[row*EPAD + c4*4] = lv;
    }
    sbar();

    // ---- R = E * P : 96 MFMA 16x16x32 (3-term split), wave tile 64x32
    f32x4 acc[4][2];
    #pragma unroll
    for (int rt = 0; rt < 4; rt++)
      #pragma unroll
      for (int ct = 0; ct < 2; ct++) acc[rt][ct] = (f32x4)(0.f);
    #pragma unroll
    for (int ks = 0; ks < 4; ks++){
      const int jb = ks*32 + lhi*8;
      short8 Ahf[4], Alf[4];
      #pragma unroll
      for (int rt = 0; rt < 4; rt++){
        const int row = wr*64 + rt*16 + l15;
        Ahf[rt] = *(const short8*)&Eh[row*EPAD + jb];
        Alf[rt] = *(const short8*)&El_[row*EPAD + jb];
      }
      short8 Bhf[2], Blf[2];
      #pragma unroll
      for (int ct = 0; ct < 2; ct++){
        const int col = wc*32 + ct*16 + l15;
        Bhf[ct] = *(const short8*)&Ph[col*EPAD + jb];
        Blf[ct] = *(const short8*)&Pl_[col*EPAD + jb];
      }
      #pragma unroll
      for (int rt = 0; rt < 4; rt++)
        #pragma unroll
        for (int ct = 0; ct < 2; ct++){
          MFMA3(acc[rt][ct], Ahf[rt], Alf[rt], Bhf[ct], Blf[ct]);
        }
    }
    sbar();   // all fragment reads done -> P/E free to overwrite

    // ---- epilogue: cross-wave rowmax via rbuf
    #pragma unroll
    for (int rt = 0; rt < 4; rt++){
      float rm[4];
      #pragma unroll
      for (int r = 0; r < 4; r++) rm[r] = fmaxf(acc[rt][0][r], acc[rt][1][r]);
      #pragma unroll
      for (int m = 1; m <= 8; m <<= 1)
        #pragma unroll
        for (int r = 0; r < 4; r++) rm[r] = fmaxf(rm[r], __shfl_xor(rm[r], m, 64));
      if (l15 == 0){
        const int row0 = wr*64 + rt*16 + lhi*4;
        #pragma unroll
        for (int r = 0; r < 4; r++) rbuf[(row0+r)*4 + wc] = rm[r];
      }
    }
    sbar();
    // ---- renorm (clamped), s update, split-bf16 writeback (transposed)
    #pragma unroll
    for (int rt = 0; rt < 4; rt++){
      const int row0 = wr*64 + rt*16 + lhi*4;
      float grm[4], inv[4];
      #pragma unroll
      for (int r = 0; r < 4; r++){
        const float4 rb = *(const float4*)&rbuf[(row0+r)*4];
        grm[r] = fmaxf(fmaxf(rb.x, rb.y), fmaxf(rb.z, rb.w));
        inv[r] = 1.0f / grm[r];
      }
      if (wc == 0 && l15 == 0){
        #pragma unroll
        for (int r = 0; r < 4; r++) sArr[row0+r] = mF + __logf(grm[r]);
      }
      #pragma unroll
      for (int ct = 0; ct < 2; ct++){
        const int col = wc*32 + ct*16 + l15;
        u16x4 hv, lv;
        #pragma unroll
        for (int r = 0; r < 4; r++){
          const float x = fmaxf(acc[rt][ct][r] * inv[r], 0.f);
          const unsigned short h = f2bf(x);
          hv[r] = h; lv[r] = f2bf(x - bf2f(h));
        }
        *(u16x4*)&Ph[col*EPAD + row0]  = hv;
        *(u16x4*)&Pl_[col*EPAD + row0] = lv;
      }
    }
    sbar();
  }

  // ---- coalesced fp32 copy-out: outP[k*128+i] = Pt[k][i] (layout tree expects)
  float* outP = ws + OFF_AP + (unsigned long)c * MATN;
  #pragma unroll
  for (int f = 0; f < 8; f++){
    const int g = t + 512*f;
    const int row = g >> 5, c4 = g & 31;
    const u16x4 hv = *(const u16x4*)&Ph[row*EPAD + c4*4];
    const u16x4 lv = *(const u16x4*)&Pl_[row*EPAD + c4*4];
    float4 v;
    v.x = bf2f(hv[0]) + bf2f(lv[0]);
    v.y = bf2f(hv[1]) + bf2f(lv[1]);
    v.z = bf2f(hv[2]) + bf2f(lv[2]);
    v.w = bf2f(hv[3]) + bf2f(lv[3]);
    ((float4*)outP)[g] = v;
  }
  if (t < 128) ws[OFF_AS + (unsigned long)c*128 + t] = sArr[t];
  #pragma unroll
  for (int m = 1; m <= 32; m <<= 1) gold += __shfl_xor(gold, m, 64);
  if (ln == 0) red[wid] = gold;
  sbar();
  if (t == 0){
    float s = 0.f;
    #pragma unroll
    for (int q = 0; q < 8; q++) s += red[q];
    ws[OFF_GP + c] = s;
  }
}

// ===================== fold: running(LDS) <- running (x) fresh(global) =====================
// MODE 0: renorm + writeback into A-LDS (row-major [i][k]).
// MODE 1: renorm + write global transposed [k][i] (scatter; small volume).
// MODE 2: raw — fill accOut/msOut, no renorm.
template<int MODE>
__device__ __forceinline__ void fold_step(const float* __restrict__ srcP,
                                          const float* __restrict__ srcS,
                                          unsigned short* Ah, unsigned short* Al,
                                          unsigned short* Bh, unsigned short* Bl,
                                          float* sArr, float* Dv, float* rbuf, float* red,
                                          float* dstP, f32x4 (*accOut)[2], float* msOut,
                                          int t)
{
  const int wid = t >> 6, ln = t & 63;
  const int l15 = ln & 15, lhi = ln >> 4;
  const int wr = wid >> 2, wc = wid & 3;

  // mS = max_j s_fresh[j];  Dv[j] = exp(s_fresh[j] - mS)
  const float sv = (t < 128) ? srcS[t] : -INFINITY;
  float lm = sv;
  #pragma unroll
  for (int m = 1; m <= 32; m <<= 1) lm = fmaxf(lm, __shfl_xor(lm, m, 64));
  if (ln == 0) red[wid] = lm;
  __syncthreads();
  float mS = red[0];
  #pragma unroll
  for (int q = 1; q < 8; q++) mS = fmaxf(mS, red[q]);
  if (t < 128) Dv[t] = __expf(sv - mS);
  __syncthreads();

  // fresh B: Pt[k][j] * d_j -> split bf16 LDS (coalesced)
  #pragma unroll
  for (int f = 0; f < 8; f++){
    const int g = t + 512*f;
    const int row = g >> 5, c4 = g & 31;
    float4 v = ((const float4*)srcP)[g];
    const float4 d = *(const float4*)&Dv[c4*4];
    v.x = fmaxf(v.x*d.x, 0.f); v.y = fmaxf(v.y*d.y, 0.f);
    v.z = fmaxf(v.z*d.z, 0.f); v.w = fmaxf(v.w*d.w, 0.f);
    u16x4 hv, lv;
    const float xs[4] = {v.x, v.y, v.z, v.w};
    #pragma unroll
    for (int e = 0; e < 4; e++){
      const unsigned short h = f2bf(xs[e]);
      hv[e] = h; lv[e] = f2bf(xs[e] - bf2f(h));
    }
    *(u16x4*)&Bh[row*EPAD + c4*4] = hv;
    *(u16x4*)&Bl[row*EPAD + c4*4] = lv;
  }
  __syncthreads();

  // R[i][k] = sum_j A[i][j] * B~[k][j]
  f32x4 acc[4][2];
  #pragma unroll
  for (int rt = 0; rt < 4; rt++)
    #pragma unroll
    for (int ct = 0; ct < 2; ct++) acc[rt][ct] = (f32x4)(0.f);
  #pragma unroll
  for (int ks = 0; ks < 4; ks++){
    const int jb = ks*32 + lhi*8;
    short8 Ahf[4], Alf[4];
    #pragma unroll
    for (int rt = 0; rt < 4; rt++){
      const int row = wr*64 + rt*16 + l15;
      Ahf[rt] = *(const short8*)&Ah[row*EPAD + jb];
      Alf[rt] = *(const short8*)&Al[row*EPAD + jb];
    }
    short8 Bhf[2], Blf[2];
    #pragma unroll
    for (int ct = 0; ct < 2; ct++){
      const int col = wc*32 + ct*16 + l15;
      Bhf[ct] = *(const short8*)&Bh[col*EPAD + jb];
      Blf[ct] = *(const short8*)&Bl[col*EPAD + jb];
    }
    #pragma unroll
    for (int rt = 0; rt < 4; rt++)
      #pragma unroll
      for (int ct = 0; ct < 2; ct++){
        MFMA3(acc[rt][ct], Ahf[rt], Alf[rt], Bhf[ct], Blf[ct]);
      }
  }
  __syncthreads();

  if (MODE == 2){
    #pragma unroll
    for (int rt = 0; rt < 4; rt++)
      #pragma unroll
      for (int ct = 0; ct < 2; ct++) accOut[rt][ct] = acc[rt][ct];
    *msOut = mS;
    return;
  }

  // cross-wave rowmax over k
  #pragma unroll
  for (int rt = 0; rt < 4; rt++){
    float rm[4];
    #pragma unroll
    for (int r = 0; r < 4; r++) rm[r] = fmaxf(acc[rt][0][r], acc[rt][1][r]);
    #pragma unroll
    for (int m = 1; m <= 8; m <<= 1)
      #pragma unroll
      for (int r = 0; r < 4; r++) rm[r] = fmaxf(rm[r], __shfl_xor(rm[r], m, 64));
    if (l15 == 0){
      const int row0 = wr*64 + rt*16 + lhi*4;
      #pragma unroll
      for (int r = 0; r < 4; r++) rbuf[(row0+r)*4 + wc] = rm[r];
    }
  }
  __syncthreads();
  #pragma unroll
  for (int rt = 0; rt < 4; rt++){
    const int row0 = wr*64 + rt*16 + lhi*4;
    float grm[4], inv[4];
    #pragma unroll
    for (int r = 0; r < 4; r++){
      const float4 rb = *(const float4*)&rbuf[(row0+r)*4];
      grm[r] = fmaxf(fmaxf(rb.x, rb.y), fmaxf(rb.z, rb.w));
      inv[r] = 1.0f / grm[r];
    }
    if (wc == 0 && l15 == 0){
      #pragma unroll
      for (int r = 0; r < 4; r++) sArr[row0+r] += mS + __logf(grm[r]);
    }
    #pragma unroll
    for (int ct = 0; ct < 2; ct++){
      const int col = wc*32 + ct*16 + l15;
      if (MODE == 0){
        #pragma unroll
        for (int r = 0; r < 4; r++){
          const float x = fmaxf(acc[rt][ct][r] * inv[r], 0.f);
          const unsigned short h = f2bf(x);
          Ah[(row0+r)*EPAD + col] = h;
          Al[(row0+r)*EPAD + col] = f2bf(x - bf2f(h));
        }
      } else {
        float4 v;
        v.x = fmaxf(acc[rt][ct][0]*inv[0], 0.f);
        v.y = fmaxf(acc[rt][ct][1]*inv[1], 0.f);
        v.z = fmaxf(acc[rt][ct][2]*inv[2], 0.f);
        v.w = fmaxf(acc[rt][ct][3]*inv[3], 0.f);
        *(float4*)&dstP[(unsigned long)col*128 + row0] = v;
      }
    }
  }
  __syncthreads();
}

#define FOLD_SHARED \
  __shared__ __align__(16) unsigned short Ah[128*EPAD]; \
  __shared__ __align__(16) unsigned short Al[128*EPAD]; \
  __shared__ __align__(16) unsigned short Bh[128*EPAD]; \
  __shared__ __align__(16) unsigned short Bl[128*EPAD]; \
  __shared__ __align__(16) float sArr[128]; \
  __shared__ __align__(16) float Dv[128]; \
  __shared__ __align__(16) float rbuf[128*4]; \
  __shared__ float red[8];

#define FOLD_INIT_IDENTITY \
  { unsigned int* z0 = (unsigned int*)Ah; unsigned int* z1 = (unsigned int*)Al; \
    for (int q = t; q < 128*EPAD/2; q += 512){ z0[q] = 0u; z1[q] = 0u; } \
    if (t < 128) sArr[t] = 0.f; } \
  __syncthreads(); \
  if (t < 128) Ah[t*EPAD + t] = 0x3F80; \
  __syncthreads();

// ============================ Phase B: 4-ary tree ============================
__global__ __launch_bounds__(512, 2) void tree4_kernel(const float* __restrict__ inP,
                                                       const float* __restrict__ inS,
                                                       float* __restrict__ outP,
                                                       float* __restrict__ outS)
{
  FOLD_SHARED
  const int t = threadIdx.x;
  const unsigned long b = blockIdx.x;
  FOLD_INIT_IDENTITY
  fold_step<0>(inP + (4*b+0)*MATN, inS + (4*b+0)*128, Ah,Al,Bh,Bl, sArr,Dv,rbuf,red, nullptr, nullptr, nullptr, t);
  fold_step<0>(inP + (4*b+1)*MATN, inS + (4*b+1)*128, Ah,Al,Bh,Bl, sArr,Dv,rbuf,red, nullptr, nullptr, nullptr, t);
  fold_step<0>(inP + (4*b+2)*MATN, inS + (4*b+2)*128, Ah,Al,Bh,Bl, sArr,Dv,rbuf,red, nullptr, nullptr, nullptr, t);
  fold_step<1>(inP + (4*b+3)*MATN, inS + (4*b+3)*128, Ah,Al,Bh,Bl, sArr,Dv,rbuf,red, outP + b*MATN, nullptr, nullptr, t);
  if (t < 128) outS[b*128 + t] = sArr[t];
}

// ============================ Phase C: final ============================
__global__ __launch_bounds__(512, 2) void final_kernel(const float* __restrict__ w,
                                                       const int* __restrict__ gmask,
                                                       const float* __restrict__ inP,
                                                       const float* __restrict__ inS,
                                                       const float* __restrict__ gp,
                                                       float* __restrict__ out)
{
  FOLD_SHARED
  const int t = threadIdx.x;
  const int wid = t >> 6, ln = t & 63;
  const int l15 = ln & 15, lhi = ln >> 4;
  const int wr = wid >> 2, wc = wid & 3;
  FOLD_INIT_IDENTITY
  fold_step<0>(inP + 0*MATN, inS + 0*128, Ah,Al,Bh,Bl, sArr,Dv,rbuf,red, nullptr, nullptr, nullptr, t);
  fold_step<0>(inP + 1*MATN, inS + 1*128, Ah,Al,Bh,Bl, sArr,Dv,rbuf,red, nullptr, nullptr, nullptr, t);
  fold_step<0>(inP + 2*MATN, inS + 2*128, Ah,Al,Bh,Bl, sArr,Dv,rbuf,red, nullptr, nullptr, nullptr, t);
  f32x4 acc[4][2]; float mS;
  fold_step<2>(inP + 3*MATN, inS + 3*128, Ah,Al,Bh,Bl, sArr,Dv,rbuf,red, nullptr, acc, &mS, t);

  // forward = LSE_{i,k}( sArr[i] + mS + log R[i][k] - w_start[i] - w_end[k] )
  float val[4][2][4];
  float lmax = -INFINITY;
  #pragma unroll
  for (int rt = 0; rt < 4; rt++){
    const int row0 = wr*64 + rt*16 + lhi*4;
    #pragma unroll
    for (int ct = 0; ct < 2; ct++){
      const int k = wc*32 + ct*16 + l15;
      const float wek = w[NEDGE - 128 + k];
      #pragma unroll
      for (int r = 0; r < 4; r++){
        const int i = row0 + r;
        const float v = sArr[i] + mS + __logf(fmaxf(acc[rt][ct][r], 0.f)) - w[i] - wek;
        val[rt][ct][r] = v;
        lmax = fmaxf(lmax, v);
      }
    }
  }
  #pragma unroll
  for (int m = 1; m <= 32; m <<= 1) lmax = fmaxf(lmax, __shfl_xor(lmax, m, 64));
  if (ln == 0) red[wid] = lmax;
  __syncthreads();
  float vmax = red[0];
  #pragma unroll
  for (int q = 1; q < 8; q++) vmax = fmaxf(vmax, red[q]);

  float es = 0.f;
  #pragma unroll
  for (int rt = 0; rt < 4; rt++)
    #pragma unroll
    for (int ct = 0; ct < 2; ct++)
      #pragma unroll
      for (int r = 0; r < 4; r++) es += __expf(val[rt][ct][r] - vmax);
  #pragma unroll
  for (int m = 1; m <= 32; m <<= 1) es += __shfl_xor(es, m, 64);
  __syncthreads();            // red reuse: all waves done reading vmax
  if (ln == 0) red[wid] = es;
  __syncthreads();
  float tot = 0.f;
  #pragma unroll
  for (int q = 0; q < 8; q++) tot += red[q];
  const float fwd = vmax + __logf(tot);

  // gold: 256 chunk partials + boundary 128+128
  float g = 0.f;
  if (t < 256) g = gp[t];
  if (t < 128) g += gmask[t] ? w[t] : 0.f;
  else if (t < 256){ const long ei = NEDGE - 256 + t; g += gmask[ei] ? w[ei] : 0.f; }
  #pragma unroll
  for (int m = 1; m <= 32; m <<= 1) g += __shfl_xor(g, m, 64);
  __syncthreads();
  if (ln == 0) red[wid] = g;
  __syncthreads();
  if (t == 0){
    float s = 0.f;
    #pragma unroll
    for (int q = 0; q < 8; q++) s += red[q];
    out[0] = s + fwd;
  }
}

extern "C" void kernel_launch(void* const* d_in, const int* in_sizes, int n_in,
                              void* d_out, int out_size, void* d_ws, size_t ws_size,
                              hipStream_t stream)
{
  (void)in_sizes; (void)n_in; (void)out_size; (void)ws_size;
  const float* w    = (const float*)d_in[0];
  const int*  gmask = (const int*)d_in[1];
  float* ws  = (float*)d_ws;      // needs >= 21.1 MB
  float* out = (float*)d_out;

  float* AP = ws + OFF_AP; float* AS = ws + OFF_AS;
  float* BP = ws + OFF_BP; float* BS = ws + OFF_BS;

  chunk_kernel<<<256, 512, 0, stream>>>(w, gmask, ws);
  tree4_kernel<<<64, 512, 0, stream>>>(AP, AS, BP, BS);   // 256 -> 64
  tree4_kernel<<<16, 512, 0, stream>>>(BP, BS, AP, AS);   //  64 -> 16
  tree4_kernel<<<4,  512, 0, stream>>>(AP, AS, BP, BS);   //  16 ->  4
  final_kernel<<<1, 512, 0, stream>>>(w, gmask, BP, BS, ws + OFF_GP, out);
}

// Round 5
// 354.094 us; speedup vs baseline: 1.3082x; 1.3082x over previous
//
#include <hip/hip_runtime.h>
#include <math.h>

// GraphLoss: W=128, L=2001 -> chain of 2000 log-semiring 128x128 matrix products
// + masked dot. out = gold + LSE_{i,k}( -w_start[i] + M_total[i][k] - w_end[k] ).
//
// Phase A (chunk, 256 blocks x ~8 layers): right-to-left fold M <- T_l (x) M via
//   split-bf16 MFMA. rep M[i][k] = s[i] + log P[i][k], P rowmax-normalized,
//   stored transposed Pt[k][i] (double-buffered LDS). Wave w owns rows 16w..16w+16
//   (full 128 cols) -> rowmax is wave-local; ONE barrier per layer.
//   Normalizer: anchor = s[0] + 8 (no block reduce; spread of s self-limits).
// Phase B: binary tree, 4 blocks/product (32-row bands): 256->128->...->1.
// Phase C: final LSE + gold.

#define MATN  16384
#define NEDGE 32768256l
#define EPAD  136        // u16 row stride (272B = 17*16B)

#define OFF_AP 0ul
#define OFF_AS (OFF_AP + 256ul*MATN)
#define OFF_BP (OFF_AS + 256ul*128)
#define OFF_BS (OFF_BP + 128ul*MATN)
#define OFF_GP (OFF_BS + 128ul*128)
// total = 6,340,864 floats = 25.4 MB of d_ws (same as round-0 layout size)

typedef __attribute__((ext_vector_type(8))) short short8;
typedef __attribute__((ext_vector_type(4))) float f32x4;
typedef __attribute__((ext_vector_type(4))) unsigned short u16x4;

__device__ __forceinline__ unsigned short f2bf(float x){
  unsigned int u = __float_as_uint(x);
  unsigned int r = (u + 0x7FFFu + ((u >> 16) & 1u)) >> 16;
  return (unsigned short)r;
}
__device__ __forceinline__ float bf2f(unsigned short h){
  return __uint_as_float(((unsigned int)h) << 16);
}

// raw barrier: lgkmcnt(0) only (LDS visibility); global prefetch stays in flight.
__device__ __forceinline__ void sbar(){
  asm volatile("s_waitcnt lgkmcnt(0)" ::: "memory");
  __builtin_amdgcn_sched_barrier(0);
  __builtin_amdgcn_s_barrier();
  __builtin_amdgcn_sched_barrier(0);
}

#define MFMA3(d, ah, al, bh, bl) \
  d = __builtin_amdgcn_mfma_f32_16x16x32_bf16(ah, bh, d, 0,0,0); \
  d = __builtin_amdgcn_mfma_f32_16x16x32_bf16(ah, bl, d, 0,0,0); \
  d = __builtin_amdgcn_mfma_f32_16x16x32_bf16(al, bh, d, 0,0,0);

// build split-bf16 short8 fragments from 8 floats
__device__ __forceinline__ void split8(const float* x, short8& h8, short8& l8){
  #pragma unroll
  for (int e = 0; e < 8; e++){
    const unsigned short h = f2bf(x[e]);
    h8[e] = (short)h;
    l8[e] = (short)f2bf(x[e] - bf2f(h));
  }
}

// ============================ Phase A: chunks ============================
__global__ __launch_bounds__(512, 2) void chunk_kernel(const float* __restrict__ w,
                                                       const int* __restrict__ gmask,
                                                       float* __restrict__ ws)
{
  __shared__ __align__(16) unsigned short Ph[2][128*EPAD];  // Pt[k][i] hi, dbuf
  __shared__ __align__(16) unsigned short Pl[2][128*EPAD];  // Pt lo
  __shared__ __align__(16) float sArr[2][128];
  __shared__ float anchor[2];
  __shared__ float red[8];

  const int t = threadIdx.x;
  const int c = blockIdx.x;
  const int lo = (c < 208) ? c*8 : 1664 + (c-208)*7;     // 208*8 + 48*7 = 2000
  const int nl = (c < 208) ? 8 : 7;

  const int wid = t >> 6, ln = t & 63;
  const int l15 = ln & 15, lhi = ln >> 4;
  const int R16 = wid * 16;          // wave's 16-row band
  const int arow = R16 + l15;        // this thread's A row

  float gold = 0.f;

  // A-pattern layer load: w[arow][lhi*8 + 32*ks + 0..7]  (64B-line clean)
  float4 cw[8]; int4 cm[8];
  {
    const float* wp = w     + 128l + (long)(lo + nl - 1)*MATN + (long)arow*128 + lhi*8;
    const int*   mp = gmask + 128l + (long)(lo + nl - 1)*MATN + (long)arow*128 + lhi*8;
    #pragma unroll
    for (int ks = 0; ks < 4; ks++){
      cw[ks*2+0] = *(const float4*)(wp + ks*32);
      cw[ks*2+1] = *(const float4*)(wp + ks*32 + 4);
      cm[ks*2+0] = *(const int4*)(mp + ks*32);
      cm[ks*2+1] = *(const int4*)(mp + ks*32 + 4);
    }
  }

  // init buffer 0: P = I (split bf16), s = 0, anchor = 8
  {
    unsigned int* z0 = (unsigned int*)&Ph[0][0];
    unsigned int* z1 = (unsigned int*)&Pl[0][0];
    for (int q = t; q < 128*EPAD/2; q += 512){ z0[q] = 0u; z1[q] = 0u; }
    if (t < 128) sArr[0][t] = 0.f;
    if (t == 0) anchor[0] = 8.f;
  }
  sbar();
  if (t < 128) Ph[0][t*EPAD + t] = 0x3F80;   // bf16 1.0
  sbar();

  for (int it = 0; it < nl; ++it){
    const int cur = it & 1, nxt = cur ^ 1;
    const float anc = anchor[cur];

    // ---- phase 1: consume layer -> gold, e = exp(s[j] - w - anchor) in regs
    float ev[8][4];
    #pragma unroll
    for (int ks = 0; ks < 4; ks++){
      const float4 sv0 = *(const float4*)&sArr[cur][ks*32 + lhi*8];
      const float4 sv1 = *(const float4*)&sArr[cur][ks*32 + lhi*8 + 4];
      {
        const float4 wv = cw[ks*2+0]; const int4 mv = cm[ks*2+0];
        gold += (mv.x ? wv.x : 0.f) + (mv.y ? wv.y : 0.f)
              + (mv.z ? wv.z : 0.f) + (mv.w ? wv.w : 0.f);
        ev[ks*2+0][0] = __expf(sv0.x - wv.x - anc);
        ev[ks*2+0][1] = __expf(sv0.y - wv.y - anc);
        ev[ks*2+0][2] = __expf(sv0.z - wv.z - anc);
        ev[ks*2+0][3] = __expf(sv0.w - wv.w - anc);
      }
      {
        const float4 wv = cw[ks*2+1]; const int4 mv = cm[ks*2+1];
        gold += (mv.x ? wv.x : 0.f) + (mv.y ? wv.y : 0.f)
              + (mv.z ? wv.z : 0.f) + (mv.w ? wv.w : 0.f);
        ev[ks*2+1][0] = __expf(sv1.x - wv.x - anc);
        ev[ks*2+1][1] = __expf(sv1.y - wv.y - anc);
        ev[ks*2+1][2] = __expf(sv1.z - wv.z - anc);
        ev[ks*2+1][3] = __expf(sv1.w - wv.w - anc);
      }
    }

    // ---- prefetch next layer (stays in flight across the raw barrier)
    if (it + 1 < nl){
      const float* wp = w     + 128l + (long)(lo + nl - 2 - it)*MATN + (long)arow*128 + lhi*8;
      const int*   mp = gmask + 128l + (long)(lo + nl - 2 - it)*MATN + (long)arow*128 + lhi*8;
      #pragma unroll
      for (int ks = 0; ks < 4; ks++){
        cw[ks*2+0] = *(const float4*)(wp + ks*32);
        cw[ks*2+1] = *(const float4*)(wp + ks*32 + 4);
        cm[ks*2+0] = *(const int4*)(mp + ks*32);
        cm[ks*2+1] = *(const int4*)(mp + ks*32 + 4);
      }
    }

    // ---- split A fragments (regs), MFMA vs P[cur]
    short8 Ahf[4], Alf[4];
    #pragma unroll
    for (int ks = 0; ks < 4; ks++) split8(&ev[ks*2][0], Ahf[ks], Alf[ks]);

    f32x4 acc[8];
    #pragma unroll
    for (int ct = 0; ct < 8; ct++) acc[ct] = (f32x4)(0.f);
    #pragma unroll
    for (int ks = 0; ks < 4; ks++){
      const int jb = ks*32 + lhi*8;
      #pragma unroll
      for (int ct = 0; ct < 8; ct++){
        const int col = ct*16 + l15;
        const short8 Bh8 = *(const short8*)&Ph[cur][col*EPAD + jb];
        const short8 Bl8 = *(const short8*)&Pl[cur][col*EPAD + jb];
        MFMA3(acc[ct], Ahf[ks], Alf[ks], Bh8, Bl8);
      }
    }

    // ---- epilogue (wave-local): rowmax over 128 cols, renorm, write P[nxt]
    float rm[4];
    #pragma unroll
    for (int r = 0; r < 4; r++){
      rm[r] = acc[0][r];
      #pragma unroll
      for (int ct = 1; ct < 8; ct++) rm[r] = fmaxf(rm[r], acc[ct][r]);
    }
    #pragma unroll
    for (int m = 1; m <= 8; m <<= 1)
      #pragma unroll
      for (int r = 0; r < 4; r++) rm[r] = fmaxf(rm[r], __shfl_xor(rm[r], m, 64));

    float inv[4], snew[4];
    #pragma unroll
    for (int r = 0; r < 4; r++){ inv[r] = 1.0f / rm[r]; snew[r] = anc + __logf(rm[r]); }
    if (l15 == 0){
      #pragma unroll
      for (int r = 0; r < 4; r++) sArr[nxt][R16 + lhi*4 + r] = snew[r];
    }
    if (t == 0) anchor[nxt] = snew[0] + 8.f;

    const int row0 = R16 + lhi*4;
    #pragma unroll
    for (int ct = 0; ct < 8; ct++){
      const int col = ct*16 + l15;
      u16x4 hv, lv;
      #pragma unroll
      for (int r = 0; r < 4; r++){
        const float x = fmaxf(acc[ct][r] * inv[r], 0.f);
        const unsigned short h = f2bf(x);
        hv[r] = h; lv[r] = f2bf(x - bf2f(h));
      }
      *(u16x4*)&Ph[nxt][col*EPAD + row0] = hv;
      *(u16x4*)&Pl[nxt][col*EPAD + row0] = lv;
    }
    sbar();
  }

  // ---- coalesced fp32 copy-out of Pt + s + gold partial
  const int fb = nl & 1;
  float* outP = ws + OFF_AP + (unsigned long)c * MATN;
  #pragma unroll
  for (int f = 0; f < 8; f++){
    const int g = t + 512*f;
    const int row = g >> 5, c4 = g & 31;
    const u16x4 hv = *(const u16x4*)&Ph[fb][row*EPAD + c4*4];
    const u16x4 lv = *(const u16x4*)&Pl[fb][row*EPAD + c4*4];
    float4 v;
    v.x = bf2f(hv[0]) + bf2f(lv[0]);
    v.y = bf2f(hv[1]) + bf2f(lv[1]);
    v.z = bf2f(hv[2]) + bf2f(lv[2]);
    v.w = bf2f(hv[3]) + bf2f(lv[3]);
    ((float4*)outP)[g] = v;
  }
  if (t < 128) ws[OFF_AS + (unsigned long)c*128 + t] = sArr[fb][t];
  #pragma unroll
  for (int m = 1; m <= 32; m <<= 1) gold += __shfl_xor(gold, m, 64);
  if (ln == 0) red[wid] = gold;
  sbar();
  if (t == 0){
    float s = 0.f;
    #pragma unroll
    for (int q = 0; q < 8; q++) s += red[q];
    ws[OFF_GP + c] = s;
  }
}

// ================= Phase B: binary pair, 4 blocks/product =================
// out[p] = in[2p] (x) in[2p+1]; block (p, band) computes rows band*32..+32.
__global__ __launch_bounds__(512, 2) void pair_kernel(const float* __restrict__ inPt,
                                                      const float* __restrict__ inS,
                                                      float* __restrict__ outPt,
                                                      float* __restrict__ outS)
{
  __shared__ __align__(16) unsigned short Bh[128*EPAD];
  __shared__ __align__(16) unsigned short Bl[128*EPAD];
  __shared__ float Dv[128];
  __shared__ float rbuf[32*4];
  __shared__ float red[8];

  const int t = threadIdx.x;
  const long p = blockIdx.x >> 2;
  const int band = blockIdx.x & 3;
  const long L = 2*p, R = 2*p + 1;

  const int wid = t >> 6, ln = t & 63;
  const int l15 = ln & 15, lhi = ln >> 4;
  const int wr2 = wid >> 2, wc = wid & 3;          // wave tile: 16 rows x 32 cols
  const int I = band*32 + wr2*16 + l15;            // output / A row

  // ---- A-fragment loads FIRST (prefetch): PA[I][j] = inPt[L][j*128 + I]
  const float* pa = inPt + L*MATN;
  float av[4][8];
  #pragma unroll
  for (int ks = 0; ks < 4; ks++)
    #pragma unroll
    for (int e = 0; e < 8; e++)
      av[ks][e] = pa[(long)(ks*32 + lhi*8 + e)*128 + I];

  // ---- mS = max sB, Dv[j] = exp(sB[j]-mS)
  const float sv = (t < 128) ? inS[R*128 + t] : -INFINITY;
  float lm = sv;
  #pragma unroll
  for (int m = 1; m <= 32; m <<= 1) lm = fmaxf(lm, __shfl_xor(lm, m, 64));
  if (ln == 0) red[wid] = lm;
  __syncthreads();
  float mS = red[0];
  #pragma unroll
  for (int q = 1; q < 8; q++) mS = fmaxf(mS, red[q]);
  if (t < 128) Dv[t] = __expf(sv - mS);
  __syncthreads();

  // ---- stage B: Bt[k][j] = PB[j][k]*D_j = inPt[R][k*128+j]*Dv[j], split bf16
  const float* pb = inPt + R*MATN;
  #pragma unroll
  for (int f = 0; f < 8; f++){
    const int g = t + 512*f;
    const int row = g >> 5, c4 = g & 31;
    float4 v = ((const float4*)pb)[g];
    const float4 d = *(const float4*)&Dv[c4*4];
    float xs[4] = { fmaxf(v.x*d.x, 0.f), fmaxf(v.y*d.y, 0.f),
                    fmaxf(v.z*d.z, 0.f), fmaxf(v.w*d.w, 0.f) };
    u16x4 hv, lv;
    #pragma unroll
    for (int e = 0; e < 4; e++){
      const unsigned short h = f2bf(xs[e]);
      hv[e] = h; lv[e] = f2bf(xs[e] - bf2f(h));
    }
    *(u16x4*)&Bh[row*EPAD + c4*4] = hv;
    *(u16x4*)&Bl[row*EPAD + c4*4] = lv;
  }
  __syncthreads();

  // ---- split A, MFMA
  short8 Ahf[4], Alf[4];
  #pragma unroll
  for (int ks = 0; ks < 4; ks++) split8(&av[ks][0], Ahf[ks], Alf[ks]);

  f32x4 acc[2];
  acc[0] = (f32x4)(0.f); acc[1] = (f32x4)(0.f);
  #pragma unroll
  for (int ks = 0; ks < 4; ks++){
    const int jb = ks*32 + lhi*8;
    #pragma unroll
    for (int ct = 0; ct < 2; ct++){
      const int col = wc*32 + ct*16 + l15;
      const short8 Bh8 = *(const short8*)&Bh[col*EPAD + jb];
      const short8 Bl8 = *(const short8*)&Bl[col*EPAD + jb];
      MFMA3(acc[ct], Ahf[ks], Alf[ks], Bh8, Bl8);
    }
  }

  // ---- cross-wave rowmax (4 wc waves)
  float rm[4];
  #pragma unroll
  for (int r = 0; r < 4; r++) rm[r] = fmaxf(acc[0][r], acc[1][r]);
  #pragma unroll
  for (int m = 1; m <= 8; m <<= 1)
    #pragma unroll
    for (int r = 0; r < 4; r++) rm[r] = fmaxf(rm[r], __shfl_xor(rm[r], m, 64));
  const int rowl0 = wr2*16 + lhi*4;
  if (l15 == 0){
    #pragma unroll
    for (int r = 0; r < 4; r++) rbuf[(rowl0+r)*4 + wc] = rm[r];
  }
  __syncthreads();

  float grm[4], inv[4];
  #pragma unroll
  for (int r = 0; r < 4; r++){
    const float4 rb = *(const float4*)&rbuf[(rowl0+r)*4];
    grm[r] = fmaxf(fmaxf(rb.x, rb.y), fmaxf(rb.z, rb.w));
    inv[r] = 1.0f / grm[r];
  }
  if (wc == 0 && l15 == 0){
    #pragma unroll
    for (int r = 0; r < 4; r++){
      const long gi = (long)band*32 + rowl0 + r;
      outS[p*128 + gi] = inS[L*128 + gi] + mS + __logf(grm[r]);
    }
  }
  // ---- write Pt out
  #pragma unroll
  for (int ct = 0; ct < 2; ct++){
    const int col = wc*32 + ct*16 + l15;
    float4 v;
    v.x = fmaxf(acc[ct][0]*inv[0], 0.f);
    v.y = fmaxf(acc[ct][1]*inv[1], 0.f);
    v.z = fmaxf(acc[ct][2]*inv[2], 0.f);
    v.w = fmaxf(acc[ct][3]*inv[3], 0.f);
    *(float4*)&outPt[p*MATN + (long)col*128 + band*32 + rowl0] = v;
  }
}

// ============================ Phase C: final ============================
__global__ __launch_bounds__(512) void final_kernel(const float* __restrict__ w,
                                                    const int* __restrict__ gmask,
                                                    const float* __restrict__ Pt,
                                                    const float* __restrict__ S,
                                                    const float* __restrict__ gp,
                                                    float* __restrict__ out)
{
  __shared__ float sw[128];
  __shared__ float red[8];
  const int t = threadIdx.x;
  const int wid = t >> 6, ln = t & 63;

  if (t < 128) sw[t] = S[t] - w[t];     // s[i] - w_start[i]
  __syncthreads();

  float vals[8][4];
  float lmax = -INFINITY;
  #pragma unroll
  for (int f = 0; f < 8; f++){
    const int g = t + 512*f;
    const int k = g >> 5, i0 = (g & 31)*4;
    const float4 pv = ((const float4*)Pt)[g];
    const float wek = w[NEDGE - 128 + k];
    vals[f][0] = sw[i0+0] + __logf(fmaxf(pv.x, 0.f)) - wek;
    vals[f][1] = sw[i0+1] + __logf(fmaxf(pv.y, 0.f)) - wek;
    vals[f][2] = sw[i0+2] + __logf(fmaxf(pv.z, 0.f)) - wek;
    vals[f][3] = sw[i0+3] + __logf(fmaxf(pv.w, 0.f)) - wek;
    #pragma unroll
    for (int e = 0; e < 4; e++) lmax = fmaxf(lmax, vals[f][e]);
  }
  #pragma unroll
  for (int m = 1; m <= 32; m <<= 1) lmax = fmaxf(lmax, __shfl_xor(lmax, m, 64));
  if (ln == 0) red[wid] = lmax;
  __syncthreads();
  float vmax = red[0];
  #pragma unroll
  for (int q = 1; q < 8; q++) vmax = fmaxf(vmax, red[q]);

  float es = 0.f;
  #pragma unroll
  for (int f = 0; f < 8; f++)
    #pragma unroll
    for (int e = 0; e < 4; e++) es += __expf(vals[f][e] - vmax);
  #pragma unroll
  for (int m = 1; m <= 32; m <<= 1) es += __shfl_xor(es, m, 64);
  __syncthreads();
  if (ln == 0) red[wid] = es;
  __syncthreads();
  float tot = 0.f;
  #pragma unroll
  for (int q = 0; q < 8; q++) tot += red[q];
  const float fwd = vmax + __logf(tot);

  // gold: 256 chunk partials + boundary 128+128
  float g = 0.f;
  if (t < 256) g = gp[t];
  if (t < 128) g += gmask[t] ? w[t] : 0.f;
  else if (t < 256){ const long ei = NEDGE - 256 + t; g += gmask[ei] ? w[ei] : 0.f; }
  #pragma unroll
  for (int m = 1; m <= 32; m <<= 1) g += __shfl_xor(g, m, 64);
  __syncthreads();
  if (ln == 0) red[wid] = g;
  __syncthreads();
  if (t == 0){
    float s = 0.f;
    #pragma unroll
    for (int q = 0; q < 8; q++) s += red[q];
    out[0] = s + fwd;
  }
}

extern "C" void kernel_launch(void* const* d_in, const int* in_sizes, int n_in,
                              void* d_out, int out_size, void* d_ws, size_t ws_size,
                              hipStream_t stream)
{
  (void)in_sizes; (void)n_in; (void)out_size; (void)ws_size;
  const float* w    = (const float*)d_in[0];
  const int*  gmask = (const int*)d_in[1];
  float* ws  = (float*)d_ws;      // needs >= 25.4 MB
  float* out = (float*)d_out;

  float* AP = ws + OFF_AP; float* AS = ws + OFF_AS;
  float* BP = ws + OFF_BP; float* BS = ws + OFF_BS;

  chunk_kernel<<<256, 512, 0, stream>>>(w, gmask, ws);          // 256 leaves -> A
  pair_kernel<<<512, 512, 0, stream>>>(AP, AS, BP, BS);         // 256 -> 128
  pair_kernel<<<256, 512, 0, stream>>>(BP, BS, AP, AS);         // 128 -> 64
  pair_kernel<<<128, 512, 0, stream>>>(AP, AS, BP, BS);         //  64 -> 32
  pair_kernel<<<64,  512, 0, stream>>>(BP, BS, AP, AS);         //  32 -> 16
  pair_kernel<<<32,  512, 0, stream>>>(AP, AS, BP, BS);         //  16 ->  8
  pair_kernel<<<16,  512, 0, stream>>>(BP, BS, AP, AS);         //   8 ->  4
  pair_kernel<<<8,   512, 0, stream>>>(AP, AS, BP, BS);         //   4 ->  2
  pair_kernel<<<4,   512, 0, stream>>>(BP, BS, AP, AS);         //   2 ->  1 (in A)
  final_kernel<<<1, 512, 0, stream>>>(w, gmask, AP, AS, ws + OFF_GP, out);
}